// Round 21
// baseline (163.713 us; speedup 1.0000x reference)
//
#include <hip/hip_runtime.h>

#define B_ 4
#define C_ 64
#define H_ 256
#define W_ 256
#define HW_ (H_*W_)
#define MID_ 12
#define NPB_ 256   // gap partial slots per image (= one per row)

typedef _Float16 h4 __attribute__((ext_vector_type(4)));
typedef _Float16 h2 __attribute__((ext_vector_type(2)));

__device__ __forceinline__ float wave_reduce64(float v) {
#pragma unroll
    for (int off = 32; off; off >>= 1) v += __shfl_xor(v, off, 64);
    return v;
}

// FilterNorm over 9 taps (float4 over 4 px); writes PIXEL-MAJOR [px][12]
__device__ __forceinline__ void fnorm4_store_pm(const float4* t9,
    const float* __restrict__ sstd, float* sp /* = sarr + (b*HW+pix)*12 */) {
    float4 mean = make_float4(0, 0, 0, 0);
#pragma unroll
    for (int t = 0; t < 9; ++t) {
        mean.x += t9[t].x; mean.y += t9[t].y; mean.z += t9[t].z; mean.w += t9[t].w;
    }
    mean.x *= (1.f/9.f); mean.y *= (1.f/9.f); mean.z *= (1.f/9.f); mean.w *= (1.f/9.f);
    float4 var = make_float4(0, 0, 0, 0);
#pragma unroll
    for (int t = 0; t < 9; ++t) {
        float dx = t9[t].x - mean.x, dy = t9[t].y - mean.y;
        float dz = t9[t].z - mean.z, dw = t9[t].w - mean.w;
        var.x = fmaf(dx, dx, var.x); var.y = fmaf(dy, dy, var.y);
        var.z = fmaf(dz, dz, var.z); var.w = fmaf(dw, dw, var.w);
    }
    const float inv[4] = {
        1.f / (sqrtf(var.x * (1.f/8.f)) + 1e-10f),
        1.f / (sqrtf(var.y * (1.f/8.f)) + 1e-10f),
        1.f / (sqrtf(var.z * (1.f/8.f)) + 1e-10f),
        1.f / (sqrtf(var.w * (1.f/8.f)) + 1e-10f)};
    const float mn[4] = {mean.x, mean.y, mean.z, mean.w};
#pragma unroll
    for (int j = 0; j < 4; ++j) {
        float v9[9];
#pragma unroll
        for (int t = 0; t < 9; ++t) {
            float raw = (j == 0) ? t9[t].x : (j == 1) ? t9[t].y : (j == 2) ? t9[t].z : t9[t].w;
            v9[t] = (raw - mn[j]) * inv[j] * sstd[t];
        }
        float* o = sp + j * 12;
        *(float4*)(o)     = make_float4(v9[0], v9[1], v9[2], v9[3]);
        *(float4*)(o + 4) = make_float4(v9[4], v9[5], v9[6], v9[7]);
        *(float4*)(o + 8) = make_float4(v9[8], 0.f, 0.f, 0.f);
    }
}

// ---------------- prep: read in once -> s (pixel-major) + gap partials ----------------
// block = 1 row, 4 waves x 16 channels; lane = 4 px. grid (H, B). (r20 structure)
template<bool HALF>
__global__ __launch_bounds__(256) void prep_kernel(const void* __restrict__ xin,
    const float* __restrict__ sw, const float* __restrict__ sb,
    const float* __restrict__ sstd, float* __restrict__ sarr, float* __restrict__ gp) {
    const int lane = threadIdx.x & 63, wv = threadIdx.x >> 6;
    const int row = blockIdx.x;
    const int b = blockIdx.y;
    const int c0 = wv * 16;
    const int pix = row * W_ + lane * 4;
    __shared__ float4 stl[3][9][64];

    float4 st[9];
#pragma unroll
    for (int t = 0; t < 9; ++t) st[t] = make_float4(0, 0, 0, 0);

    const size_t base = (size_t)b * C_ * HW_ + pix;
    const float* xbF = (const float*)xin + base;
    const _Float16* xbH = (const _Float16*)xin + base;

#define LOAD4(DST, CC) do {                                                   \
        if constexpr (HALF) {                                                 \
            h4 v_ = *(const h4*)(xbH + (size_t)(CC) * HW_);                   \
            DST = make_float4((float)v_[0], (float)v_[1],                     \
                              (float)v_[2], (float)v_[3]);                    \
        } else {                                                              \
            DST = *(const float4*)(xbF + (size_t)(CC) * HW_);                 \
        }                                                                     \
    } while (0)

#define PREP_COMP(BUF, CC) do {                                               \
        _Pragma("unroll")                                                     \
        for (int i_ = 0; i_ < 4; ++i_) {                                      \
            const int c_ = (CC) + i_;                                         \
            float4 v_ = BUF[i_];                                              \
            _Pragma("unroll")                                                 \
            for (int t_ = 0; t_ < 9; ++t_) {                                  \
                const float wt_ = sw[t_ * C_ + c_];                           \
                st[t_].x = fmaf(v_.x, wt_, st[t_].x);                         \
                st[t_].y = fmaf(v_.y, wt_, st[t_].y);                         \
                st[t_].z = fmaf(v_.z, wt_, st[t_].z);                         \
                st[t_].w = fmaf(v_.w, wt_, st[t_].w);                         \
            }                                                                 \
            float g_ = wave_reduce64(((v_.x + v_.y) + (v_.z + v_.w)));        \
            if (lane == 0) gp[((size_t)b * C_ + c_) * NPB_ + blockIdx.x] = g_; \
        }                                                                     \
    } while (0)

    float4 vA[4], vB[4];
#pragma unroll
    for (int i = 0; i < 4; ++i) LOAD4(vA[i], c0 + i);
#pragma unroll
    for (int k = 0; k < 16; k += 8) {
#pragma unroll
        for (int i = 0; i < 4; ++i) LOAD4(vB[i], c0 + k + 4 + i);
        PREP_COMP(vA, c0 + k);
        if (k + 8 < 16) {
#pragma unroll
            for (int i = 0; i < 4; ++i) LOAD4(vA[i], c0 + k + 8 + i);
        }
        PREP_COMP(vB, c0 + k + 4);
    }
#undef LOAD4
#undef PREP_COMP

    if (wv) {
#pragma unroll
        for (int t = 0; t < 9; ++t) stl[wv - 1][t][lane] = st[t];
    }
    __syncthreads();
    if (wv == 0) {
#pragma unroll
        for (int t = 0; t < 9; ++t) {
            float bb = sb[t];
#pragma unroll
            for (int j = 0; j < 3; ++j) {
                float4 o = stl[j][t][lane];
                st[t].x += o.x; st[t].y += o.y; st[t].z += o.z; st[t].w += o.w;
            }
            st[t].x += bb; st[t].y += bb; st[t].z += bb; st[t].w += bb;
        }
        fnorm4_store_pm(st, sstd, sarr + ((size_t)b * HW_ + pix) * 12);
    }
}

// ------ cfk: reduce gap partials + SE MLP + FilterNorm -> cf (B,C,12 padded) ------
__global__ __launch_bounds__(256) void cfk(const float* __restrict__ gp,
    const float* __restrict__ cw1, const float* __restrict__ cb1,
    const float* __restrict__ cw2, const float* __restrict__ cb2,
    const float* __restrict__ cstd, float* __restrict__ cf) {
    const int tid = threadIdx.x;
    const int b = tid >> 6, c = tid & 63;
    __shared__ float gsm[B_][C_];
    __shared__ float hsm[B_][MID_];
    {
        const float4* p4 = (const float4*)(gp + ((size_t)b * C_ + c) * NPB_);
        float s = 0.f;
#pragma unroll 8
        for (int i = 0; i < NPB_ / 4; ++i) { float4 v = p4[i]; s += (v.x + v.y) + (v.z + v.w); }
        gsm[b][c] = s * (1.f / HW_);
    }
    __syncthreads();
    if (tid < B_ * MID_) {
        int b2 = tid / MID_, m = tid % MID_;
        float a = cb1[m];
        for (int cc = 0; cc < C_; ++cc) a = fmaf(gsm[b2][cc], cw1[m * C_ + cc], a);
        hsm[b2][m] = fmaxf(a, 0.f);
    }
    __syncthreads();
    float v[9];
    float mean = 0.f;
#pragma unroll
    for (int t = 0; t < 9; ++t) {
        int o = c * 9 + t;
        float a = cb2[o];
#pragma unroll
        for (int m = 0; m < MID_; ++m) a = fmaf(hsm[b][m], cw2[o * MID_ + m], a);
        v[t] = a;
        mean += a;
    }
    mean *= (1.f / 9.f);
    float var = 0.f;
#pragma unroll
    for (int t = 0; t < 9; ++t) { float d = v[t] - mean; var += d * d; }
    float inv = 1.f / (sqrtf(var * (1.f / 8.f)) + 1e-10f);
    float* o12 = cf + ((size_t)b * C_ + c) * 12;
#pragma unroll
    for (int t = 0; t < 9; ++t) o12[t] = (v[t] - mean) * inv * cstd[c * 9 + t];
    o12[9] = 0.f; o12[10] = 0.f; o12[11] = 0.f;
}

// ---------- apply: 2 px/thread, 4 channels/block, SAME block count as r15 ----------
// block = 128x4 px tile, 4 channels; grid (2, H/4, B*16) = 8192 blocks.
// Per channel-row: 1 float2 (mid) + 2 scalars cover both px -> 9 VMEM/ch/2px.
// s is pixel-major: both pixels' 24 s-floats contiguous -> 6 float4 loads.
template<bool RELU, bool RESID, bool INH, bool OUTH>
__global__ __launch_bounds__(256) void apply_kernel(const void* __restrict__ in,
    const float* __restrict__ sarr, const float* __restrict__ cf,
    const float* __restrict__ resid, void* __restrict__ out) {
    const int lane = threadIdx.x & 63, wv = threadIdx.x >> 6;
    const int col0 = blockIdx.x * 128 + lane * 2;     // even
    const int row = blockIdx.y * 4 + wv;
    const int z = blockIdx.z;
    const int b = z >> 4;
    const int c0 = (z & 15) * 4;
    const int pix = row * W_ + col0;

    const bool rup = row > 0, rdn = row < H_ - 1;
    const bool cl = col0 > 0;
    const bool cr = (col0 + 1) < (W_ - 1);

    // s taps for both pixels: 6 contiguous float4s (pixel-major)
    float s0a[9], s0b[9];
    {
        const float* sp = sarr + ((size_t)b * HW_ + pix) * 12;
        float4 q0 = *(const float4*)(sp);
        float4 q1 = *(const float4*)(sp + 4);
        float4 q2 = *(const float4*)(sp + 8);
        float4 q3 = *(const float4*)(sp + 12);
        float4 q4 = *(const float4*)(sp + 16);
        float4 q5 = *(const float4*)(sp + 20);
        s0a[0] = q0.x; s0a[1] = q0.y; s0a[2] = q0.z; s0a[3] = q0.w;
        s0a[4] = q1.x; s0a[5] = q1.y; s0a[6] = q1.z; s0a[7] = q1.w;
        s0a[8] = q2.x;
        s0b[0] = q3.x; s0b[1] = q3.y; s0b[2] = q3.z; s0b[3] = q3.w;
        s0b[4] = q4.x; s0b[5] = q4.y; s0b[6] = q4.z; s0b[7] = q4.w;
        s0b[8] = q5.x;
#pragma unroll
        for (int t = 0; t < 3; ++t) {
            if (!rup) { s0a[t] = 0.f; s0b[t] = 0.f; }
            if (!rdn) { s0a[t + 6] = 0.f; s0b[t + 6] = 0.f; }
        }
        if (!cl) { s0a[0] = 0.f; s0a[3] = 0.f; s0a[6] = 0.f; }
        if (!cr) { s0b[2] = 0.f; s0b[5] = 0.f; s0b[8] = 0.f; }
    }

    // per-row offsets (element units within the channel plane)
    int offM[3], offL[3], offR[3];
    {
        const int ro[3] = {rup ? -W_ : 0, 0, rdn ? W_ : 0};
#pragma unroll
        for (int dr = 0; dr < 3; ++dr) {
            offM[dr] = pix + ro[dr];
            offL[dr] = offM[dr] + (cl ? -1 : 0);
            offR[dr] = offM[dr] + (cr ? 2 : 0);
        }
    }

    const size_t cbase = ((size_t)b * C_ + c0) * HW_;
    const float* inF = (const float*)in + cbase;
    const _Float16* inH = (const _Float16*)in + cbase;
    const float* cfb = cf + ((size_t)b * C_ + c0) * 12;
    const float* rb  = RESID ? ((const float*)resid + cbase + pix) : nullptr;
    float* outF = (float*)out + cbase + pix;
    _Float16* outH = (_Float16*)out + cbase + pix;

    // all 4 channels' inputs loaded upfront (36 VMEM in flight)
    float mm[4][3][2], ll[4][3], rr[4][3];
    float2 rv[4];

#pragma unroll
    for (int c = 0; c < 4; ++c) {
        if constexpr (INH) {
            const _Float16* p = inH + (size_t)c * HW_;
#pragma unroll
            for (int dr = 0; dr < 3; ++dr) {
                h2 mv = *(const h2*)(p + offM[dr]);
                mm[c][dr][0] = (float)mv[0]; mm[c][dr][1] = (float)mv[1];
                ll[c][dr] = (float)p[offL[dr]];
                rr[c][dr] = (float)p[offR[dr]];
            }
        } else {
            const float* p = inF + (size_t)c * HW_;
#pragma unroll
            for (int dr = 0; dr < 3; ++dr) {
                float2 mv = *(const float2*)(p + offM[dr]);
                mm[c][dr][0] = mv.x; mm[c][dr][1] = mv.y;
                ll[c][dr] = p[offL[dr]];
                rr[c][dr] = p[offR[dr]];
            }
        }
        if (RESID) rv[c] = *(const float2*)(rb + (size_t)c * HW_);
    }

#pragma unroll
    for (int c = 0; c < 4; ++c) {
        const float* cfc = cfb + (size_t)c * 12;
        float a0 = 0.f, a1 = 0.f;
#pragma unroll
        for (int dr = 0; dr < 3; ++dr) {
            const int t = dr * 3;
            a0 = fmaf(ll[c][dr]    * s0a[t],     cfc[t],     a0);
            a0 = fmaf(mm[c][dr][0] * s0a[t + 1], cfc[t + 1], a0);
            a0 = fmaf(mm[c][dr][1] * s0a[t + 2], cfc[t + 2], a0);
            a1 = fmaf(mm[c][dr][0] * s0b[t],     cfc[t],     a1);
            a1 = fmaf(mm[c][dr][1] * s0b[t + 1], cfc[t + 1], a1);
            a1 = fmaf(rr[c][dr]    * s0b[t + 2], cfc[t + 2], a1);
        }
        if (RELU) { a0 = fmaxf(a0, 0.f); a1 = fmaxf(a1, 0.f); }
        if (RESID) { a0 += rv[c].x; a1 += rv[c].y; }
        if constexpr (OUTH) {
            h2 o; o[0] = (_Float16)a0; o[1] = (_Float16)a1;
            *(h2*)(outH + (size_t)c * HW_) = o;
        } else {
            *(float2*)(outF + (size_t)c * HW_) = make_float2(a0, a1);
        }
    }
}

extern "C" void kernel_launch(void* const* d_in, const int* in_sizes, int n_in,
                              void* d_out, int out_size, void* d_ws, size_t ws_size,
                              hipStream_t stream) {
    const float* x     = (const float*)d_in[0];
    const float* sw1   = (const float*)d_in[1];
    const float* sb1   = (const float*)d_in[2];
    const float* sstd1 = (const float*)d_in[3];
    const float* cw1_1 = (const float*)d_in[4];
    const float* cb1_1 = (const float*)d_in[5];
    const float* cw2_1 = (const float*)d_in[6];
    const float* cb2_1 = (const float*)d_in[7];
    const float* cstd1 = (const float*)d_in[8];
    const float* sw2   = (const float*)d_in[9];
    const float* sb2   = (const float*)d_in[10];
    const float* sstd2 = (const float*)d_in[11];
    const float* cw1_2 = (const float*)d_in[12];
    const float* cb1_2 = (const float*)d_in[13];
    const float* cw2_2 = (const float*)d_in[14];
    const float* cb2_2 = (const float*)d_in[15];
    const float* cstd2 = (const float*)d_in[16];
    float* outp = (float*)d_out;

    const size_t n_out1 = (size_t)B_ * C_ * HW_;     // 16,777,216 (fp16)
    const size_t n_s    = (size_t)B_ * HW_ * 12;     // 3,145,728 (pixel-major)
    const size_t n_cf   = (size_t)B_ * C_ * 12;      // 3,072 (padded)
    const size_t n_gp   = (size_t)B_ * C_ * NPB_;    // 65,536
    const size_t need = n_out1 * sizeof(_Float16)
                      + (2 * n_s + 2 * n_cf + 2 * n_gp) * sizeof(float);
    if (ws_size < need) return;

    _Float16* out1h = (_Float16*)d_ws;
    float* s1  = (float*)((char*)d_ws + n_out1 * sizeof(_Float16));
    float* s2  = s1 + n_s;
    float* cf1 = s2 + n_s;
    float* cf2 = cf1 + n_cf;
    float* gp1 = cf2 + n_cf;
    float* gp2 = gp1 + n_gp;

    dim3 gprep(H_, B_);                     // 1024 blocks
    dim3 gapply(2, H_ / 4, B_ * 16);        // 8192 blocks, 4 ch x 2 px

    // pass 1
    prep_kernel<false><<<gprep, 256, 0, stream>>>(x, sw1, sb1, sstd1, s1, gp1);
    cfk<<<1, 256, 0, stream>>>(gp1, cw1_1, cb1_1, cw2_1, cb2_1, cstd1, cf1);
    apply_kernel<true, false, false, true><<<gapply, 256, 0, stream>>>(
        x, s1, cf1, nullptr, out1h);
    // pass 2
    prep_kernel<true><<<gprep, 256, 0, stream>>>(out1h, sw2, sb2, sstd2, s2, gp2);
    cfk<<<1, 256, 0, stream>>>(gp2, cw1_2, cb1_2, cw2_2, cb2_2, cstd2, cf2);
    apply_kernel<false, true, true, false><<<gapply, 256, 0, stream>>>(
        out1h, s2, cf2, x, outp);
}